// Round 13
// baseline (881.040 us; speedup 1.0000x reference)
//
#include <hip/hip_runtime.h>
#include <hip/hip_bf16.h>

#define BB  512
#define TT  128
#define CC  96
#define HH  6
#define HSZ 16
#define LL  6
#define FFD 384
#define VV  65
#define BT  (BB * TT)   // 65536 rows

using short8  = __attribute__((ext_vector_type(8))) short;   // 8 bf16 (4 VGPRs)
using short4v = __attribute__((ext_vector_type(4))) short;   // 4 bf16
using f32x4   = __attribute__((ext_vector_type(4))) float;
using half4   = __attribute__((ext_vector_type(4))) _Float16;

static __device__ __forceinline__ unsigned short f2bf(float f) {
  union { float f; unsigned u; } v{f};
  unsigned r = (v.u + 0x7fff + ((v.u >> 16) & 1)) >> 16;   // RNE
  return (unsigned short)r;
}
static __device__ __forceinline__ float b2f(unsigned short h) {
  union { unsigned u; float f; } v{(unsigned)h << 16};
  return v.f;
}
static __device__ __forceinline__ unsigned short f2h(float f) {
  union { _Float16 h; unsigned short u; } c; c.h = (_Float16)f; return c.u;
}

// ---------------- embedding: x[b,t,:] = tok_emb[idx[b,t],:] + pos_emb[t,:] (fp32) -------
__global__ __launch_bounds__(256) void embed_kernel(
    const int* __restrict__ idx, const float* __restrict__ tok,
    const float* __restrict__ pos, float* __restrict__ x) {
  int gid = blockIdx.x * 256 + threadIdx.x;      // over BT*24 float4s
  int r = gid / 24, c4 = gid % 24;
  int t = r & (TT - 1);
  int token = idx[r];
  const float4 a = *(const float4*)&tok[token * CC + c4 * 4];
  const float4 p = *(const float4*)&pos[t * CC + c4 * 4];
  float4 o;
  o.x = a.x + p.x; o.y = a.y + p.y; o.z = a.z + p.z; o.w = a.w + p.w;
  *(float4*)&x[(size_t)r * CC + c4 * 4] = o;
}

// ---------------- weight pack ------------------------------------------------------------
// jobs 0-5:  QKV fused bf16 x32-frags [cb][ks][lane][8]
// jobs 6-11: proj bf16 x32-frags
// jobs 12-17: W1^T f16 x16-A-frags [fft(24)][kt(6)][lane][4]  (A[m=ff][k=c] = W1[c][ff])
// jobs 18-23: W2^T f16 x16-A-frags [ct(6)][kt(24)][lane][4]   (A[m=c][k=ff] = W2[ff][c])
// job 24: lm head bf16 x32-frags, N padded to 80
__global__ __launch_bounds__(256) void pack_w(
    const float* __restrict__ Wq, const float* __restrict__ Wk,
    const float* __restrict__ Wv, const float* __restrict__ Wp,
    const float* __restrict__ W1, const float* __restrict__ W2,
    const float* __restrict__ Wlm, unsigned short* __restrict__ out) {
  int job = blockIdx.y;
  int e = blockIdx.x * 256 + threadIdx.x;
  int sz; size_t obase;
  if (job < 6)       { sz = 27648; obase = (size_t)job * 27648; }
  else if (job < 12) { sz = 9216;  obase = 165888 + (size_t)(job - 6) * 9216; }
  else if (job < 18) { sz = 36864; obase = 221184 + (size_t)(job - 12) * 36864; }
  else if (job < 24) { sz = 36864; obase = 442368 + (size_t)(job - 18) * 36864; }
  else               { sz = 7680;  obase = 663552; }
  if (e >= sz) return;

  if (job < 12 || job >= 24) {     // bf16 x32-fragment jobs
    int j = e & 7, lane = (e >> 3) & 63, rest = e >> 9;
    int ks = rest % 3, cb = rest / 3;
    int k = ks * 32 + (lane >> 4) * 8 + j;
    int n = cb * 16 + (lane & 15);
    float val = 0.f;
    if (job < 6) {                 // fused QKV, N=288
      int src = n / 96, nn = n % 96;
      const float* W = (src == 0) ? Wq : (src == 1) ? Wk : Wv;
      val = W[((size_t)(job * 6 + (nn >> 4)) * 96 + k) * 16 + (nn & 15)];
    } else if (job < 12) {         // proj [96][96]
      val = Wp[(size_t)(job - 6) * 9216 + k * 96 + n];
    } else {                       // lm head [96][65] padded to N=80
      if (n < 65) val = Wlm[k * 65 + n];
    }
    out[obase + e] = f2bf(val);
  } else if (job < 18) {           // W1^T f16
    int j = e & 3, lane = (e >> 2) & 63, rest = e >> 8;
    int kt = rest % 6, ft = rest / 6;
    int k = kt * 16 + (lane >> 4) * 4 + j;     // C dim
    int ff = ft * 16 + (lane & 15);
    out[obase + e] = f2h(W1[(size_t)(job - 12) * 36864 + k * FFD + ff]);
  } else {                         // W2^T f16
    int j = e & 3, lane = (e >> 2) & 63, rest = e >> 8;
    int kt = rest % 24, ct = rest / 24;
    int ff = kt * 16 + (lane >> 4) * 4 + j;    // FF dim
    int c = ct * 16 + (lane & 15);
    out[obase + e] = f2h(W2[(size_t)(job - 18) * 36864 + ff * CC + c]);
  }
}

// ---------------- MFMA GEMM: out[r][n] = act(sum_k A[r][k]*W[k][n] + bias) (+res) -------
template<int K, int N, int NS, bool BIAS, bool RELU, bool RES, bool OUTBF>
__global__ __launch_bounds__(256) void mfma_gemm(
    const unsigned short* __restrict__ A, const unsigned short* __restrict__ Wpk,
    const float* __restrict__ bias, const float* __restrict__ res, void* __restrict__ out) {
  constexpr int KS = K / 32;
  const int lane = threadIdx.x & 63;
  const int wave = threadIdx.x >> 6;
  const int r0 = blockIdx.x * 64 + wave * 16;
  const int c15 = lane & 15, kg = lane >> 4;
  short8 a[KS];
  const unsigned short* ap = A + (size_t)(r0 + c15) * K + kg * 8;
#pragma unroll
  for (int ks = 0; ks < KS; ++ks) a[ks] = *(const short8*)(ap + ks * 32);
  const short8* wf = (const short8*)Wpk;
#pragma unroll 1
  for (int cb = 0; cb < N / 16; ++cb) {
    f32x4 acc = {0.f, 0.f, 0.f, 0.f};
#pragma unroll
    for (int ks = 0; ks < KS; ++ks) {
      short8 b = wf[(cb * KS + ks) * 64 + lane];
      acc = __builtin_amdgcn_mfma_f32_16x16x32_bf16(a[ks], b, acc, 0, 0, 0);
    }
    int n = cb * 16 + c15;
#pragma unroll
    for (int i = 0; i < 4; ++i) {
      int row = r0 + kg * 4 + i;
      if (NS == N || n < NS) {
        float v = acc[i];
        if (BIAS) v += bias[n];
        if (RELU) v = fmaxf(v, 0.f);
        if (RES)  v += res[(size_t)row * NS + n];
        if (OUTBF) ((unsigned short*)out)[(size_t)row * NS + n] = f2bf(v);
        else       ((float*)out)[(size_t)row * NS + n] = v;
      }
    }
  }
}

// ---------------- fused LayerNorm + MFMA GEMM (K=96) ------------------------------------
template<int N, int NS, bool BIAS, bool RELU, bool OUTBF>
__global__ __launch_bounds__(256) void ln_gemm(
    const float* __restrict__ X, const unsigned short* __restrict__ Wpk,
    const float* __restrict__ gamma, const float* __restrict__ beta,
    const float* __restrict__ bias, void* __restrict__ out) {
  const int lane = threadIdx.x & 63;
  const int wave = threadIdx.x >> 6;
  const int r0 = blockIdx.x * 64 + wave * 16;
  const int c15 = lane & 15, kg = lane >> 4;
  const float* xp = X + (size_t)(r0 + c15) * CC + kg * 8;
  float xv[24];
  float s = 0.f, s2 = 0.f;
#pragma unroll
  for (int ks = 0; ks < 3; ++ks) {
    float4 lo = *(const float4*)(xp + ks * 32);
    float4 hi = *(const float4*)(xp + ks * 32 + 4);
    xv[ks * 8 + 0] = lo.x; xv[ks * 8 + 1] = lo.y; xv[ks * 8 + 2] = lo.z; xv[ks * 8 + 3] = lo.w;
    xv[ks * 8 + 4] = hi.x; xv[ks * 8 + 5] = hi.y; xv[ks * 8 + 6] = hi.z; xv[ks * 8 + 7] = hi.w;
  }
#pragma unroll
  for (int i = 0; i < 24; ++i) { s += xv[i]; s2 += xv[i] * xv[i]; }
  s  += __shfl_xor(s, 16);  s  += __shfl_xor(s, 32);
  s2 += __shfl_xor(s2, 16); s2 += __shfl_xor(s2, 32);
  const float mean = s * (1.f / 96.f);
  const float rs = rsqrtf(s2 * (1.f / 96.f) - mean * mean + 1e-5f);
  short8 a[3];
#pragma unroll
  for (int ks = 0; ks < 3; ++ks) {
    const int kb = ks * 32 + kg * 8;
    float4 glo = *(const float4*)&gamma[kb];
    float4 ghi = *(const float4*)&gamma[kb + 4];
    float4 blo = *(const float4*)&beta[kb];
    float4 bhi = *(const float4*)&beta[kb + 4];
    const float gg[8] = {glo.x, glo.y, glo.z, glo.w, ghi.x, ghi.y, ghi.z, ghi.w};
    const float bb[8] = {blo.x, blo.y, blo.z, blo.w, bhi.x, bhi.y, bhi.z, bhi.w};
#pragma unroll
    for (int j = 0; j < 8; ++j)
      a[ks][j] = (short)f2bf((xv[ks * 8 + j] - mean) * rs * gg[j] + bb[j]);
  }
  const short8* wf = (const short8*)Wpk;
#pragma unroll 1
  for (int cb = 0; cb < N / 16; ++cb) {
    f32x4 acc = {0.f, 0.f, 0.f, 0.f};
#pragma unroll
    for (int ks = 0; ks < 3; ++ks) {
      short8 b = wf[(cb * 3 + ks) * 64 + lane];
      acc = __builtin_amdgcn_mfma_f32_16x16x32_bf16(a[ks], b, acc, 0, 0, 0);
    }
    int n = cb * 16 + c15;
#pragma unroll
    for (int i = 0; i < 4; ++i) {
      int row = r0 + kg * 4 + i;
      if (NS == N || n < NS) {
        float v = acc[i];
        if (BIAS) v += bias[n];
        if (RELU) v = fmaxf(v, 0.f);
        if (OUTBF) ((unsigned short*)out)[(size_t)row * NS + n] = f2bf(v);
        else       ((float*)out)[(size_t)row * NS + n] = v;
      }
    }
  }
}

// ---------------- fused FF block: x += relu(LN(x)W1+b1)W2 + b2 --------------------------
// Transposed 16x16x16f16 chain; C-layout == B-frag layout. Phase 1 and phase 2 are
// INTERLEAVED per ff-tile: compute p = relu(W1t·LN^T + b1) for one 16-wide ff tile,
// immediately contract it into acc2 (6 MFMAs), discard p. No bp1[24] buffer -> -48 VGPR;
// launch_bounds(256,4) forces VGPR<=128 for 4 waves/SIMD. Two phase-1 accumulators
// (even/odd kt) double the chain ILP; next ft's chain overlaps this ft's acc2 burst.
__global__ __launch_bounds__(256, 4) void ff_fused(
    const float* __restrict__ X, const unsigned short* __restrict__ W1t,
    const unsigned short* __restrict__ W2t,
    const float* __restrict__ g2, const float* __restrict__ be2,
    const float* __restrict__ b1, const float* __restrict__ b2,
    float* __restrict__ xo) {
  const int lane = threadIdx.x & 63;
  const int wave = threadIdx.x >> 6;
  const int q = lane & 15, g = lane >> 4;
  const size_t row = (size_t)blockIdx.x * 64 + wave * 16 + q;
  const float* xp = X + row * CC;

  // lane's x slice: cols kt*16 + g*4 + j  (j=0..3, kt=0..5) — also the residual slice
  float xv[24];
  float s = 0.f, s2 = 0.f;
#pragma unroll
  for (int kt = 0; kt < 6; ++kt) {
    const float4 v = *(const float4*)(xp + kt * 16 + g * 4);
    xv[kt * 4 + 0] = v.x; xv[kt * 4 + 1] = v.y; xv[kt * 4 + 2] = v.z; xv[kt * 4 + 3] = v.w;
    s += v.x + v.y + v.z + v.w;
    s2 += v.x * v.x + v.y * v.y + v.z * v.z + v.w * v.w;
  }
  s  += __shfl_xor(s, 16);  s  += __shfl_xor(s, 32);
  s2 += __shfl_xor(s2, 16); s2 += __shfl_xor(s2, 32);
  const float mean = s * (1.f / 96.f);
  const float rs = rsqrtf(s2 * (1.f / 96.f) - mean * mean + 1e-5f);

  // LN^T B-frags: bln[kt][j] = LN[row][kt*16+g*4+j]
  half4 bln[6];
#pragma unroll
  for (int kt = 0; kt < 6; ++kt) {
    const float4 gm = *(const float4*)&g2[kt * 16 + g * 4];
    const float4 bt = *(const float4*)&be2[kt * 16 + g * 4];
    bln[kt][0] = (_Float16)((xv[kt * 4 + 0] - mean) * rs * gm.x + bt.x);
    bln[kt][1] = (_Float16)((xv[kt * 4 + 1] - mean) * rs * gm.y + bt.y);
    bln[kt][2] = (_Float16)((xv[kt * 4 + 2] - mean) * rs * gm.z + bt.z);
    bln[kt][3] = (_Float16)((xv[kt * 4 + 3] - mean) * rs * gm.w + bt.w);
  }

  const half4* w1f = (const half4*)W1t;
  const half4* w2f = (const half4*)W2t;
  const f32x4 zero = {0.f, 0.f, 0.f, 0.f};
  f32x4 acc2[6];
#pragma unroll
  for (int ct = 0; ct < 6; ++ct) acc2[ct] = zero;

#pragma unroll
  for (int ft = 0; ft < 24; ++ft) {
    // phase 1 tile: two independent 3-deep chains
    f32x4 a1a = zero, a1b = zero;
#pragma unroll
    for (int kt = 0; kt < 6; kt += 2) {
      a1a = __builtin_amdgcn_mfma_f32_16x16x16f16(w1f[(ft * 6 + kt) * 64 + lane],     bln[kt],     a1a, 0, 0, 0);
      a1b = __builtin_amdgcn_mfma_f32_16x16x16f16(w1f[(ft * 6 + kt + 1) * 64 + lane], bln[kt + 1], a1b, 0, 0, 0);
    }
    const float4 bb = *(const float4*)&b1[ft * 16 + g * 4];
    half4 p;
    p[0] = (_Float16)fmaxf(a1a[0] + a1b[0] + bb.x, 0.f);
    p[1] = (_Float16)fmaxf(a1a[1] + a1b[1] + bb.y, 0.f);
    p[2] = (_Float16)fmaxf(a1a[2] + a1b[2] + bb.z, 0.f);
    p[3] = (_Float16)fmaxf(a1a[3] + a1b[3] + bb.w, 0.f);
    // phase 2: contract this ff tile into all 6 c-tiles (independent MFMAs)
#pragma unroll
    for (int ct = 0; ct < 6; ++ct)
      acc2[ct] = __builtin_amdgcn_mfma_f32_16x16x16f16(w2f[(ct * 24 + ft) * 64 + lane], p, acc2[ct], 0, 0, 0);
  }

  // epilogue: x[row][c] = xv + dx + b2   (residual straight from registers)
  float* op = xo + row * CC;
#pragma unroll
  for (int ct = 0; ct < 6; ++ct) {
    const float4 bb = *(const float4*)&b2[ct * 16 + g * 4];
    float4 o;
    o.x = xv[ct * 4 + 0] + acc2[ct][0] + bb.x;
    o.y = xv[ct * 4 + 1] + acc2[ct][1] + bb.y;
    o.z = xv[ct * 4 + 2] + acc2[ct][2] + bb.z;
    o.w = xv[ct * 4 + 3] + acc2[ct][3] + bb.w;
    *(float4*)(op + ct * 16 + g * 4) = o;
  }
}

// ---------------- MFMA attention: one block per (b,head), 4 waves ----------------------
__global__ __launch_bounds__(256) void attn_mfma(
    const unsigned short* __restrict__ qkv, unsigned short* __restrict__ aout) {
  const int b = blockIdx.x / HH, hd = blockIdx.x % HH;
  __shared__ _Float16 Ks[TT][20];   // K (f16); reused for O^T after barrier
  __shared__ _Float16 Vs[TT][20];
  const size_t base = (size_t)b * TT * 288 + hd * HSZ;
  const int t = threadIdx.x;
  const int r = t >> 1, part = t & 1;

  {
    const short8 k8 = *(const short8*)&qkv[base + (size_t)r * 288 + 96  + part * 8];
    const short8 v8 = *(const short8*)&qkv[base + (size_t)r * 288 + 192 + part * 8];
    half4 klo, khi, vlo, vhi;
#pragma unroll
    for (int j = 0; j < 4; ++j) {
      klo[j] = (_Float16)b2f((unsigned short)k8[j]);
      khi[j] = (_Float16)b2f((unsigned short)k8[4 + j]);
      vlo[j] = (_Float16)b2f((unsigned short)v8[j]);
      vhi[j] = (_Float16)b2f((unsigned short)v8[4 + j]);
    }
    *(half4*)&Ks[r][part * 8]     = klo;
    *(half4*)&Ks[r][part * 8 + 4] = khi;
    *(half4*)&Vs[r][part * 8]     = vlo;
    *(half4*)&Vs[r][part * 8 + 4] = vhi;
  }
  __syncthreads();

  const int lane = t & 63;
  const int w = t >> 6;
  const int q15 = lane & 15, g = lane >> 4;
  const int qt0 = w, qt1 = 7 - w;

  half4 bq[2];
  {
    const short4v qa = *(const short4v*)&qkv[base + (size_t)(qt0 * 16 + q15) * 288 + g * 4];
    const short4v qb = *(const short4v*)&qkv[base + (size_t)(qt1 * 16 + q15) * 288 + g * 4];
#pragma unroll
    for (int j = 0; j < 4; ++j) {
      bq[0][j] = (_Float16)b2f((unsigned short)qa[j]);
      bq[1][j] = (_Float16)b2f((unsigned short)qb[j]);
    }
  }

  half4 ak[8];
#pragma unroll
  for (int kt = 0; kt < 8; ++kt)
    ak[kt] = *(const half4*)&Ks[kt * 16 + q15][g * 4];

  const f32x4 zero = {0.f, 0.f, 0.f, 0.f};
  f32x4 sx[2][8];
#pragma unroll
  for (int kt = 0; kt < 8; ++kt) {
    sx[0][kt] = __builtin_amdgcn_mfma_f32_16x16x16f16(ak[kt], bq[0], zero, 0, 0, 0);
    sx[1][kt] = __builtin_amdgcn_mfma_f32_16x16x16f16(ak[kt], bq[1], zero, 0, 0, 0);
  }

  half4 bp[2][8];
#pragma unroll
  for (int s = 0; s < 2; ++s) {
    const int qt = s ? qt1 : qt0;
    const int qg = qt * 16 + q15;
    float mx = -3.0e38f;
#pragma unroll
    for (int kt = 0; kt < 8; ++kt)
#pragma unroll
      for (int i = 0; i < 4; ++i) {
        int kg = kt * 16 + g * 4 + i;
        float v = (kg <= qg) ? sx[s][kt][i] * 0.25f : -3.0e38f;
        sx[s][kt][i] = v;
        mx = fmaxf(mx, v);
      }
    mx = fmaxf(mx, __shfl_xor(mx, 16));
    mx = fmaxf(mx, __shfl_xor(mx, 32));
    float sum = 0.f;
#pragma unroll
    for (int kt = 0; kt < 8; ++kt)
#pragma unroll
      for (int i = 0; i < 4; ++i) {
        float p = __expf(sx[s][kt][i] - mx);
        sx[s][kt][i] = p;
        sum += p;
      }
    sum += __shfl_xor(sum, 16);
    sum += __shfl_xor(sum, 32);
    float inv = 1.f / sum;
#pragma unroll
    for (int kt = 0; kt < 8; ++kt)
#pragma unroll
      for (int i = 0; i < 4; ++i)
        bp[s][kt][i] = (_Float16)(sx[s][kt][i] * inv);
  }

  f32x4 o0 = zero, o1 = zero;
#pragma unroll
  for (int kt = 0; kt < 8; ++kt) {
    half4 av;
#pragma unroll
    for (int j = 0; j < 4; ++j) av[j] = Vs[kt * 16 + g * 4 + j][q15];
    o0 = __builtin_amdgcn_mfma_f32_16x16x16f16(av, bp[0][kt], o0, 0, 0, 0);
    o1 = __builtin_amdgcn_mfma_f32_16x16x16f16(av, bp[1][kt], o1, 0, 0, 0);
  }

  __syncthreads();
  {
    half4 w0, w1;
#pragma unroll
    for (int i = 0; i < 4; ++i) { w0[i] = (_Float16)o0[i]; w1[i] = (_Float16)o1[i]; }
    *(half4*)&Ks[qt0 * 16 + q15][g * 4] = w0;
    *(half4*)&Ks[qt1 * 16 + q15][g * 4] = w1;
  }
  __syncthreads();
  {
    const half4 a0 = *(const half4*)&Ks[r][part * 8];
    const half4 a1 = *(const half4*)&Ks[r][part * 8 + 4];
    short8 pk;
#pragma unroll
    for (int j = 0; j < 4; ++j) {
      pk[j]     = (short)f2bf((float)a0[j]);
      pk[4 + j] = (short)f2bf((float)a1[j]);
    }
    *(short8*)&aout[(size_t)(b * TT + r) * CC + hd * HSZ + part * 8] = pk;
  }
}

extern "C" void kernel_launch(void* const* d_in, const int* in_sizes, int n_in,
                              void* d_out, int out_size, void* d_ws, size_t ws_size,
                              hipStream_t stream) {
  const int*   idx  = (const int*)d_in[0];
  const float* tok  = (const float*)d_in[1];
  const float* pos  = (const float*)d_in[2];
  const float* Wq   = (const float*)d_in[3];
  const float* Wk   = (const float*)d_in[4];
  const float* Wv   = (const float*)d_in[5];
  const float* Wp   = (const float*)d_in[6];
  const float* bp   = (const float*)d_in[7];
  const float* W1   = (const float*)d_in[8];
  const float* b1   = (const float*)d_in[9];
  const float* W2   = (const float*)d_in[10];
  const float* b2   = (const float*)d_in[11];
  const float* ln1g = (const float*)d_in[12];
  const float* ln1b = (const float*)d_in[13];
  const float* ln2g = (const float*)d_in[14];
  const float* ln2b = (const float*)d_in[15];
  const float* lnfg = (const float*)d_in[16];
  const float* lnfb = (const float*)d_in[17];
  const float* Wlm  = (const float*)d_in[18];
  const float* blm  = (const float*)d_in[19];

  // workspace: x fp32 | h bf16 | qkv bf16 | packed weights
  float* x = (float*)d_ws;
  unsigned short* h    = (unsigned short*)(x + (size_t)BT * CC);
  unsigned short* qkvb = h + (size_t)BT * CC;
  unsigned short* wpk  = qkvb + (size_t)BT * FFD;
  const size_t OQKV = 0, OPRJ = 165888, OFF1 = 221184, OFF2 = 442368, OLM = 663552;

  pack_w<<<dim3(144, 25), 256, 0, stream>>>(Wq, Wk, Wv, Wp, W1, W2, Wlm, wpk);
  embed_kernel<<<BT * 24 / 256, 256, 0, stream>>>(idx, tok, pos, x);

  for (int l = 0; l < LL; ++l) {
    ln_gemm<288, 288, false, false, true>
        <<<BT / 64, 256, 0, stream>>>(x, wpk + OQKV + (size_t)l * 27648,
                                      ln1g + l * CC, ln1b + l * CC, nullptr, qkvb);
    attn_mfma<<<BB * HH, 256, 0, stream>>>(qkvb, h);
    mfma_gemm<96, 96, 96, true, false, true, false>
        <<<BT / 64, 256, 0, stream>>>(h, wpk + OPRJ + (size_t)l * 9216, bp + l * CC, x, x);
    ff_fused<<<BT / 64, 256, 0, stream>>>(x, wpk + OFF1 + (size_t)l * 36864,
                                          wpk + OFF2 + (size_t)l * 36864,
                                          ln2g + l * CC, ln2b + l * CC,
                                          b1 + l * FFD, b2 + l * CC, x);
  }

  ln_gemm<80, 65, true, false, false>
      <<<BT / 64, 256, 0, stream>>>(x, wpk + OLM, lnfg, lnfb, blm, (float*)d_out);
}

// Round 15
// 746.932 us; speedup vs baseline: 1.1795x; 1.1795x over previous
//
#include <hip/hip_runtime.h>
#include <hip/hip_bf16.h>

#define BB  512
#define TT  128
#define CC  96
#define HH  6
#define HSZ 16
#define LL  6
#define FFD 384
#define VV  65
#define BT  (BB * TT)   // 65536 rows

using short8  = __attribute__((ext_vector_type(8))) short;   // 8 bf16 (4 VGPRs)
using short4v = __attribute__((ext_vector_type(4))) short;   // 4 bf16
using f32x4   = __attribute__((ext_vector_type(4))) float;
using half4   = __attribute__((ext_vector_type(4))) _Float16;

static __device__ __forceinline__ unsigned short f2bf(float f) {
  union { float f; unsigned u; } v{f};
  unsigned r = (v.u + 0x7fff + ((v.u >> 16) & 1)) >> 16;   // RNE
  return (unsigned short)r;
}
static __device__ __forceinline__ float b2f(unsigned short h) {
  union { unsigned u; float f; } v{(unsigned)h << 16};
  return v.f;
}
static __device__ __forceinline__ unsigned short f2h(float f) {
  union { _Float16 h; unsigned short u; } c; c.h = (_Float16)f; return c.u;
}

// ---------------- embedding: x[b,t,:] = tok_emb[idx[b,t],:] + pos_emb[t,:] (fp32) -------
__global__ __launch_bounds__(256) void embed_kernel(
    const int* __restrict__ idx, const float* __restrict__ tok,
    const float* __restrict__ pos, float* __restrict__ x) {
  int gid = blockIdx.x * 256 + threadIdx.x;      // over BT*24 float4s
  int r = gid / 24, c4 = gid % 24;
  int t = r & (TT - 1);
  int token = idx[r];
  const float4 a = *(const float4*)&tok[token * CC + c4 * 4];
  const float4 p = *(const float4*)&pos[t * CC + c4 * 4];
  float4 o;
  o.x = a.x + p.x; o.y = a.y + p.y; o.z = a.z + p.z; o.w = a.w + p.w;
  *(float4*)&x[(size_t)r * CC + c4 * 4] = o;
}

// ---------------- weight pack ------------------------------------------------------------
// jobs 0-5:  QKV fused bf16 x32-frags [cb][ks][lane][8]
// jobs 6-11: proj bf16 x32-frags
// jobs 12-17: W1^T f16 x16-A-frags [fft(24)][kt(6)][lane][4]  (A[m=ff][k=c] = W1[c][ff])
// jobs 18-23: W2^T f16 x16-A-frags [ct(6)][kt(24)][lane][4]   (A[m=c][k=ff] = W2[ff][c])
// job 24: lm head bf16 x32-frags, N padded to 80
__global__ __launch_bounds__(256) void pack_w(
    const float* __restrict__ Wq, const float* __restrict__ Wk,
    const float* __restrict__ Wv, const float* __restrict__ Wp,
    const float* __restrict__ W1, const float* __restrict__ W2,
    const float* __restrict__ Wlm, unsigned short* __restrict__ out) {
  int job = blockIdx.y;
  int e = blockIdx.x * 256 + threadIdx.x;
  int sz; size_t obase;
  if (job < 6)       { sz = 27648; obase = (size_t)job * 27648; }
  else if (job < 12) { sz = 9216;  obase = 165888 + (size_t)(job - 6) * 9216; }
  else if (job < 18) { sz = 36864; obase = 221184 + (size_t)(job - 12) * 36864; }
  else if (job < 24) { sz = 36864; obase = 442368 + (size_t)(job - 18) * 36864; }
  else               { sz = 7680;  obase = 663552; }
  if (e >= sz) return;

  if (job < 12 || job >= 24) {     // bf16 x32-fragment jobs
    int j = e & 7, lane = (e >> 3) & 63, rest = e >> 9;
    int ks = rest % 3, cb = rest / 3;
    int k = ks * 32 + (lane >> 4) * 8 + j;
    int n = cb * 16 + (lane & 15);
    float val = 0.f;
    if (job < 6) {                 // fused QKV, N=288
      int src = n / 96, nn = n % 96;
      const float* W = (src == 0) ? Wq : (src == 1) ? Wk : Wv;
      val = W[((size_t)(job * 6 + (nn >> 4)) * 96 + k) * 16 + (nn & 15)];
    } else if (job < 12) {         // proj [96][96]
      val = Wp[(size_t)(job - 6) * 9216 + k * 96 + n];
    } else {                       // lm head [96][65] padded to N=80
      if (n < 65) val = Wlm[k * 65 + n];
    }
    out[obase + e] = f2bf(val);
  } else if (job < 18) {           // W1^T f16
    int j = e & 3, lane = (e >> 2) & 63, rest = e >> 8;
    int kt = rest % 6, ft = rest / 6;
    int k = kt * 16 + (lane >> 4) * 4 + j;     // C dim
    int ff = ft * 16 + (lane & 15);
    out[obase + e] = f2h(W1[(size_t)(job - 12) * 36864 + k * FFD + ff]);
  } else {                         // W2^T f16
    int j = e & 3, lane = (e >> 2) & 63, rest = e >> 8;
    int kt = rest % 24, ct = rest / 24;
    int ff = kt * 16 + (lane >> 4) * 4 + j;    // FF dim
    int c = ct * 16 + (lane & 15);
    out[obase + e] = f2h(W2[(size_t)(job - 18) * 36864 + ff * CC + c]);
  }
}

// ---------------- MFMA GEMM: out[r][n] = act(sum_k A[r][k]*W[k][n] + bias) (+res) -------
template<int K, int N, int NS, bool BIAS, bool RELU, bool RES, bool OUTBF>
__global__ __launch_bounds__(256) void mfma_gemm(
    const unsigned short* __restrict__ A, const unsigned short* __restrict__ Wpk,
    const float* __restrict__ bias, const float* __restrict__ res, void* __restrict__ out) {
  constexpr int KS = K / 32;
  const int lane = threadIdx.x & 63;
  const int wave = threadIdx.x >> 6;
  const int r0 = blockIdx.x * 64 + wave * 16;
  const int c15 = lane & 15, kg = lane >> 4;
  short8 a[KS];
  const unsigned short* ap = A + (size_t)(r0 + c15) * K + kg * 8;
#pragma unroll
  for (int ks = 0; ks < KS; ++ks) a[ks] = *(const short8*)(ap + ks * 32);
  const short8* wf = (const short8*)Wpk;
#pragma unroll 1
  for (int cb = 0; cb < N / 16; ++cb) {
    f32x4 acc = {0.f, 0.f, 0.f, 0.f};
#pragma unroll
    for (int ks = 0; ks < KS; ++ks) {
      short8 b = wf[(cb * KS + ks) * 64 + lane];
      acc = __builtin_amdgcn_mfma_f32_16x16x32_bf16(a[ks], b, acc, 0, 0, 0);
    }
    int n = cb * 16 + c15;
#pragma unroll
    for (int i = 0; i < 4; ++i) {
      int row = r0 + kg * 4 + i;
      if (NS == N || n < NS) {
        float v = acc[i];
        if (BIAS) v += bias[n];
        if (RELU) v = fmaxf(v, 0.f);
        if (RES)  v += res[(size_t)row * NS + n];
        if (OUTBF) ((unsigned short*)out)[(size_t)row * NS + n] = f2bf(v);
        else       ((float*)out)[(size_t)row * NS + n] = v;
      }
    }
  }
}

// ---------------- fused LayerNorm + MFMA GEMM (K=96) ------------------------------------
template<int N, int NS, bool BIAS, bool RELU, bool OUTBF>
__global__ __launch_bounds__(256) void ln_gemm(
    const float* __restrict__ X, const unsigned short* __restrict__ Wpk,
    const float* __restrict__ gamma, const float* __restrict__ beta,
    const float* __restrict__ bias, void* __restrict__ out) {
  const int lane = threadIdx.x & 63;
  const int wave = threadIdx.x >> 6;
  const int r0 = blockIdx.x * 64 + wave * 16;
  const int c15 = lane & 15, kg = lane >> 4;
  const float* xp = X + (size_t)(r0 + c15) * CC + kg * 8;
  float xv[24];
  float s = 0.f, s2 = 0.f;
#pragma unroll
  for (int ks = 0; ks < 3; ++ks) {
    float4 lo = *(const float4*)(xp + ks * 32);
    float4 hi = *(const float4*)(xp + ks * 32 + 4);
    xv[ks * 8 + 0] = lo.x; xv[ks * 8 + 1] = lo.y; xv[ks * 8 + 2] = lo.z; xv[ks * 8 + 3] = lo.w;
    xv[ks * 8 + 4] = hi.x; xv[ks * 8 + 5] = hi.y; xv[ks * 8 + 6] = hi.z; xv[ks * 8 + 7] = hi.w;
  }
#pragma unroll
  for (int i = 0; i < 24; ++i) { s += xv[i]; s2 += xv[i] * xv[i]; }
  s  += __shfl_xor(s, 16);  s  += __shfl_xor(s, 32);
  s2 += __shfl_xor(s2, 16); s2 += __shfl_xor(s2, 32);
  const float mean = s * (1.f / 96.f);
  const float rs = rsqrtf(s2 * (1.f / 96.f) - mean * mean + 1e-5f);
  short8 a[3];
#pragma unroll
  for (int ks = 0; ks < 3; ++ks) {
    const int kb = ks * 32 + kg * 8;
    float4 glo = *(const float4*)&gamma[kb];
    float4 ghi = *(const float4*)&gamma[kb + 4];
    float4 blo = *(const float4*)&beta[kb];
    float4 bhi = *(const float4*)&beta[kb + 4];
    const float gg[8] = {glo.x, glo.y, glo.z, glo.w, ghi.x, ghi.y, ghi.z, ghi.w};
    const float bb[8] = {blo.x, blo.y, blo.z, blo.w, bhi.x, bhi.y, bhi.z, bhi.w};
#pragma unroll
    for (int j = 0; j < 8; ++j)
      a[ks][j] = (short)f2bf((xv[ks * 8 + j] - mean) * rs * gg[j] + bb[j]);
  }
  const short8* wf = (const short8*)Wpk;
#pragma unroll 1
  for (int cb = 0; cb < N / 16; ++cb) {
    f32x4 acc = {0.f, 0.f, 0.f, 0.f};
#pragma unroll
    for (int ks = 0; ks < 3; ++ks) {
      short8 b = wf[(cb * 3 + ks) * 64 + lane];
      acc = __builtin_amdgcn_mfma_f32_16x16x32_bf16(a[ks], b, acc, 0, 0, 0);
    }
    int n = cb * 16 + c15;
#pragma unroll
    for (int i = 0; i < 4; ++i) {
      int row = r0 + kg * 4 + i;
      if (NS == N || n < NS) {
        float v = acc[i];
        if (BIAS) v += bias[n];
        if (RELU) v = fmaxf(v, 0.f);
        if (OUTBF) ((unsigned short*)out)[(size_t)row * NS + n] = f2bf(v);
        else       ((float*)out)[(size_t)row * NS + n] = v;
      }
    }
  }
}

// ---------------- fused FF block: x += relu(LN(x)W1+b1)W2 + b2 --------------------------
// Transposed 16x16x16f16 chain; C-layout == B-frag layout. Phase 1 and phase 2 are
// INTERLEAVED per ff-tile: compute p = relu(W1t·LN^T + b1) for one 16-wide ff tile,
// immediately contract it into acc2 (6 MFMAs), discard p. No bp1[24] buffer (-48 VGPR
// vs buffered). launch_bounds(256,2): natural VGPR ~110-130 -> 4 waves/SIMD WITHOUT
// spill (r13 lesson: (256,4) clamped to 64 VGPR -> 85 MB spill traffic, 70 us).
__global__ __launch_bounds__(256, 2) void ff_fused(
    const float* __restrict__ X, const unsigned short* __restrict__ W1t,
    const unsigned short* __restrict__ W2t,
    const float* __restrict__ g2, const float* __restrict__ be2,
    const float* __restrict__ b1, const float* __restrict__ b2,
    float* __restrict__ xo) {
  const int lane = threadIdx.x & 63;
  const int wave = threadIdx.x >> 6;
  const int q = lane & 15, g = lane >> 4;
  const size_t row = (size_t)blockIdx.x * 64 + wave * 16 + q;
  const float* xp = X + row * CC;

  // lane's x slice: cols kt*16 + g*4 + j  (j=0..3, kt=0..5) — also the residual slice
  float xv[24];
  float s = 0.f, s2 = 0.f;
#pragma unroll
  for (int kt = 0; kt < 6; ++kt) {
    const float4 v = *(const float4*)(xp + kt * 16 + g * 4);
    xv[kt * 4 + 0] = v.x; xv[kt * 4 + 1] = v.y; xv[kt * 4 + 2] = v.z; xv[kt * 4 + 3] = v.w;
    s += v.x + v.y + v.z + v.w;
    s2 += v.x * v.x + v.y * v.y + v.z * v.z + v.w * v.w;
  }
  s  += __shfl_xor(s, 16);  s  += __shfl_xor(s, 32);
  s2 += __shfl_xor(s2, 16); s2 += __shfl_xor(s2, 32);
  const float mean = s * (1.f / 96.f);
  const float rs = rsqrtf(s2 * (1.f / 96.f) - mean * mean + 1e-5f);

  // LN^T B-frags: bln[kt][j] = LN[row][kt*16+g*4+j]
  half4 bln[6];
#pragma unroll
  for (int kt = 0; kt < 6; ++kt) {
    const float4 gm = *(const float4*)&g2[kt * 16 + g * 4];
    const float4 bt = *(const float4*)&be2[kt * 16 + g * 4];
    bln[kt][0] = (_Float16)((xv[kt * 4 + 0] - mean) * rs * gm.x + bt.x);
    bln[kt][1] = (_Float16)((xv[kt * 4 + 1] - mean) * rs * gm.y + bt.y);
    bln[kt][2] = (_Float16)((xv[kt * 4 + 2] - mean) * rs * gm.z + bt.z);
    bln[kt][3] = (_Float16)((xv[kt * 4 + 3] - mean) * rs * gm.w + bt.w);
  }

  const half4* w1f = (const half4*)W1t;
  const half4* w2f = (const half4*)W2t;
  const f32x4 zero = {0.f, 0.f, 0.f, 0.f};
  f32x4 acc2[6];
#pragma unroll
  for (int ct = 0; ct < 6; ++ct) acc2[ct] = zero;

#pragma unroll
  for (int ft = 0; ft < 24; ++ft) {
    // phase 1 tile: two independent 3-deep chains
    f32x4 a1a = zero, a1b = zero;
#pragma unroll
    for (int kt = 0; kt < 6; kt += 2) {
      a1a = __builtin_amdgcn_mfma_f32_16x16x16f16(w1f[(ft * 6 + kt) * 64 + lane],     bln[kt],     a1a, 0, 0, 0);
      a1b = __builtin_amdgcn_mfma_f32_16x16x16f16(w1f[(ft * 6 + kt + 1) * 64 + lane], bln[kt + 1], a1b, 0, 0, 0);
    }
    const float4 bb = *(const float4*)&b1[ft * 16 + g * 4];
    half4 p;
    p[0] = (_Float16)fmaxf(a1a[0] + a1b[0] + bb.x, 0.f);
    p[1] = (_Float16)fmaxf(a1a[1] + a1b[1] + bb.y, 0.f);
    p[2] = (_Float16)fmaxf(a1a[2] + a1b[2] + bb.z, 0.f);
    p[3] = (_Float16)fmaxf(a1a[3] + a1b[3] + bb.w, 0.f);
    // phase 2: contract this ff tile into all 6 c-tiles (independent MFMAs)
#pragma unroll
    for (int ct = 0; ct < 6; ++ct)
      acc2[ct] = __builtin_amdgcn_mfma_f32_16x16x16f16(w2f[(ct * 24 + ft) * 64 + lane], p, acc2[ct], 0, 0, 0);
  }

  // epilogue: x[row][c] = xv + dx + b2   (residual straight from registers)
  float* op = xo + row * CC;
#pragma unroll
  for (int ct = 0; ct < 6; ++ct) {
    const float4 bb = *(const float4*)&b2[ct * 16 + g * 4];
    float4 o;
    o.x = xv[ct * 4 + 0] + acc2[ct][0] + bb.x;
    o.y = xv[ct * 4 + 1] + acc2[ct][1] + bb.y;
    o.z = xv[ct * 4 + 2] + acc2[ct][2] + bb.z;
    o.w = xv[ct * 4 + 3] + acc2[ct][3] + bb.w;
    *(float4*)(op + ct * 16 + g * 4) = o;
  }
}

// ---------------- MFMA attention: one block per (b,head), 4 waves ----------------------
__global__ __launch_bounds__(256) void attn_mfma(
    const unsigned short* __restrict__ qkv, unsigned short* __restrict__ aout) {
  const int b = blockIdx.x / HH, hd = blockIdx.x % HH;
  __shared__ _Float16 Ks[TT][20];   // K (f16); reused for O^T after barrier
  __shared__ _Float16 Vs[TT][20];
  const size_t base = (size_t)b * TT * 288 + hd * HSZ;
  const int t = threadIdx.x;
  const int r = t >> 1, part = t & 1;

  {
    const short8 k8 = *(const short8*)&qkv[base + (size_t)r * 288 + 96  + part * 8];
    const short8 v8 = *(const short8*)&qkv[base + (size_t)r * 288 + 192 + part * 8];
    half4 klo, khi, vlo, vhi;
#pragma unroll
    for (int j = 0; j < 4; ++j) {
      klo[j] = (_Float16)b2f((unsigned short)k8[j]);
      khi[j] = (_Float16)b2f((unsigned short)k8[4 + j]);
      vlo[j] = (_Float16)b2f((unsigned short)v8[j]);
      vhi[j] = (_Float16)b2f((unsigned short)v8[4 + j]);
    }
    *(half4*)&Ks[r][part * 8]     = klo;
    *(half4*)&Ks[r][part * 8 + 4] = khi;
    *(half4*)&Vs[r][part * 8]     = vlo;
    *(half4*)&Vs[r][part * 8 + 4] = vhi;
  }
  __syncthreads();

  const int lane = t & 63;
  const int w = t >> 6;
  const int q15 = lane & 15, g = lane >> 4;
  const int qt0 = w, qt1 = 7 - w;

  half4 bq[2];
  {
    const short4v qa = *(const short4v*)&qkv[base + (size_t)(qt0 * 16 + q15) * 288 + g * 4];
    const short4v qb = *(const short4v*)&qkv[base + (size_t)(qt1 * 16 + q15) * 288 + g * 4];
#pragma unroll
    for (int j = 0; j < 4; ++j) {
      bq[0][j] = (_Float16)b2f((unsigned short)qa[j]);
      bq[1][j] = (_Float16)b2f((unsigned short)qb[j]);
    }
  }

  half4 ak[8];
#pragma unroll
  for (int kt = 0; kt < 8; ++kt)
    ak[kt] = *(const half4*)&Ks[kt * 16 + q15][g * 4];

  const f32x4 zero = {0.f, 0.f, 0.f, 0.f};
  f32x4 sx[2][8];
#pragma unroll
  for (int kt = 0; kt < 8; ++kt) {
    sx[0][kt] = __builtin_amdgcn_mfma_f32_16x16x16f16(ak[kt], bq[0], zero, 0, 0, 0);
    sx[1][kt] = __builtin_amdgcn_mfma_f32_16x16x16f16(ak[kt], bq[1], zero, 0, 0, 0);
  }

  half4 bp[2][8];
#pragma unroll
  for (int s = 0; s < 2; ++s) {
    const int qt = s ? qt1 : qt0;
    const int qg = qt * 16 + q15;
    float mx = -3.0e38f;
#pragma unroll
    for (int kt = 0; kt < 8; ++kt)
#pragma unroll
      for (int i = 0; i < 4; ++i) {
        int kg = kt * 16 + g * 4 + i;
        float v = (kg <= qg) ? sx[s][kt][i] * 0.25f : -3.0e38f;
        sx[s][kt][i] = v;
        mx = fmaxf(mx, v);
      }
    mx = fmaxf(mx, __shfl_xor(mx, 16));
    mx = fmaxf(mx, __shfl_xor(mx, 32));
    float sum = 0.f;
#pragma unroll
    for (int kt = 0; kt < 8; ++kt)
#pragma unroll
      for (int i = 0; i < 4; ++i) {
        float p = __expf(sx[s][kt][i] - mx);
        sx[s][kt][i] = p;
        sum += p;
      }
    sum += __shfl_xor(sum, 16);
    sum += __shfl_xor(sum, 32);
    float inv = 1.f / sum;
#pragma unroll
    for (int kt = 0; kt < 8; ++kt)
#pragma unroll
      for (int i = 0; i < 4; ++i)
        bp[s][kt][i] = (_Float16)(sx[s][kt][i] * inv);
  }

  f32x4 o0 = zero, o1 = zero;
#pragma unroll
  for (int kt = 0; kt < 8; ++kt) {
    half4 av;
#pragma unroll
    for (int j = 0; j < 4; ++j) av[j] = Vs[kt * 16 + g * 4 + j][q15];
    o0 = __builtin_amdgcn_mfma_f32_16x16x16f16(av, bp[0][kt], o0, 0, 0, 0);
    o1 = __builtin_amdgcn_mfma_f32_16x16x16f16(av, bp[1][kt], o1, 0, 0, 0);
  }

  __syncthreads();
  {
    half4 w0, w1;
#pragma unroll
    for (int i = 0; i < 4; ++i) { w0[i] = (_Float16)o0[i]; w1[i] = (_Float16)o1[i]; }
    *(half4*)&Ks[qt0 * 16 + q15][g * 4] = w0;
    *(half4*)&Ks[qt1 * 16 + q15][g * 4] = w1;
  }
  __syncthreads();
  {
    const half4 a0 = *(const half4*)&Ks[r][part * 8];
    const half4 a1 = *(const half4*)&Ks[r][part * 8 + 4];
    short8 pk;
#pragma unroll
    for (int j = 0; j < 4; ++j) {
      pk[j]     = (short)f2bf((float)a0[j]);
      pk[4 + j] = (short)f2bf((float)a1[j]);
    }
    *(short8*)&aout[(size_t)(b * TT + r) * CC + hd * HSZ + part * 8] = pk;
  }
}

extern "C" void kernel_launch(void* const* d_in, const int* in_sizes, int n_in,
                              void* d_out, int out_size, void* d_ws, size_t ws_size,
                              hipStream_t stream) {
  const int*   idx  = (const int*)d_in[0];
  const float* tok  = (const float*)d_in[1];
  const float* pos  = (const float*)d_in[2];
  const float* Wq   = (const float*)d_in[3];
  const float* Wk   = (const float*)d_in[4];
  const float* Wv   = (const float*)d_in[5];
  const float* Wp   = (const float*)d_in[6];
  const float* bp   = (const float*)d_in[7];
  const float* W1   = (const float*)d_in[8];
  const float* b1   = (const float*)d_in[9];
  const float* W2   = (const float*)d_in[10];
  const float* b2   = (const float*)d_in[11];
  const float* ln1g = (const float*)d_in[12];
  const float* ln1b = (const float*)d_in[13];
  const float* ln2g = (const float*)d_in[14];
  const float* ln2b = (const float*)d_in[15];
  const float* lnfg = (const float*)d_in[16];
  const float* lnfb = (const float*)d_in[17];
  const float* Wlm  = (const float*)d_in[18];
  const float* blm  = (const float*)d_in[19];

  // workspace: x fp32 | h bf16 | qkv bf16 | packed weights
  float* x = (float*)d_ws;
  unsigned short* h    = (unsigned short*)(x + (size_t)BT * CC);
  unsigned short* qkvb = h + (size_t)BT * CC;
  unsigned short* wpk  = qkvb + (size_t)BT * FFD;
  const size_t OQKV = 0, OPRJ = 165888, OFF1 = 221184, OFF2 = 442368, OLM = 663552;

  pack_w<<<dim3(144, 25), 256, 0, stream>>>(Wq, Wk, Wv, Wp, W1, W2, Wlm, wpk);
  embed_kernel<<<BT * 24 / 256, 256, 0, stream>>>(idx, tok, pos, x);

  for (int l = 0; l < LL; ++l) {
    ln_gemm<288, 288, false, false, true>
        <<<BT / 64, 256, 0, stream>>>(x, wpk + OQKV + (size_t)l * 27648,
                                      ln1g + l * CC, ln1b + l * CC, nullptr, qkvb);
    attn_mfma<<<BB * HH, 256, 0, stream>>>(qkvb, h);
    mfma_gemm<96, 96, 96, true, false, true, false>
        <<<BT / 64, 256, 0, stream>>>(h, wpk + OPRJ + (size_t)l * 9216, bp + l * CC, x, x);
    ff_fused<<<BT / 64, 256, 0, stream>>>(x, wpk + OFF1 + (size_t)l * 36864,
                                          wpk + OFF2 + (size_t)l * 36864,
                                          ln2g + l * CC, ln2b + l * CC,
                                          b1 + l * FFD, b2 + l * CC, x);
  }

  ln_gemm<80, 65, true, false, false>
      <<<BT / 64, 256, 0, stream>>>(x, wpk + OLM, lnfg, lnfb, blm, (float*)d_out);
}